// Round 1
// baseline (1453.433 us; speedup 1.0000x reference)
//
#include <hip/hip_runtime.h>

// GCN: N=100000 nodes, E=3.2M edges, 512 -> 128 (relu) -> 40
// Pipeline: deg/norm -> CSR build (scan+scatter) -> GEMM1 -> SpMM1(+b1,relu)
//           -> GEMM2 -> SpMM2(+b2)

#define NFEAT 512
#define NHID  128
#define NCLS  40

// ---------------- degree + counts (per-edge atomics) ----------------
__global__ void edge_deg_count(const int* __restrict__ row, const int* __restrict__ col,
                               const float* __restrict__ w,
                               float* __restrict__ deg, int* __restrict__ counts, int E) {
    int e = blockIdx.x * 256 + threadIdx.x;
    if (e < E) {
        int c = col[e];
        atomicAdd(&deg[c], w[e]);
        atomicAdd(&counts[c], 1);
    }
}

// dis = rsqrt(deg + 1)  (self-loop weight 1 guarantees deg_total >= 1 > 0)
__global__ void dis_kernel(const float* __restrict__ deg, float* __restrict__ dis, int N) {
    int i = blockIdx.x * 256 + threadIdx.x;
    if (i < N) dis[i] = rsqrtf(deg[i] + 1.0f);
}

// ---------------- exclusive scan (3 kernels) ----------------
__global__ void scan_blocks(const int* __restrict__ counts, int* __restrict__ rowptr,
                            int* __restrict__ bsums, int N) {
    __shared__ int s[256];
    int tid = threadIdx.x;
    int i = blockIdx.x * 256 + tid;
    int v = (i < N) ? counts[i] : 0;
    s[tid] = v;
    __syncthreads();
    for (int off = 1; off < 256; off <<= 1) {
        int t = (tid >= off) ? s[tid - off] : 0;
        __syncthreads();
        s[tid] += t;
        __syncthreads();
    }
    if (i < N) rowptr[i] = s[tid] - v;               // exclusive
    if (tid == 255) bsums[blockIdx.x] = s[255];      // block total
}

__global__ void scan_bsums(int* __restrict__ bsums, int nb) {
    __shared__ int s[512];
    int t = threadIdx.x;
    int v = (t < nb) ? bsums[t] : 0;
    s[t] = v;
    __syncthreads();
    for (int off = 1; off < 512; off <<= 1) {
        int u = (t >= off) ? s[t - off] : 0;
        __syncthreads();
        s[t] += u;
        __syncthreads();
    }
    if (t < nb) bsums[t] = s[t] - v;                 // exclusive
}

__global__ void add_offsets(int* __restrict__ rowptr, const int* __restrict__ bsums,
                            int N, int E) {
    int i = blockIdx.x * 256 + threadIdx.x;
    if (i < N) rowptr[i] += bsums[blockIdx.x];
    if (i == 0) rowptr[N] = E;
}

// ---------------- scatter edges into CSR (by dst) ----------------
__global__ void scatter_edges(const int* __restrict__ row, const int* __restrict__ col,
                              const float* __restrict__ w, const float* __restrict__ dis,
                              const int* __restrict__ rowptr, int* __restrict__ fill,
                              int* __restrict__ csr_src, float* __restrict__ csr_norm, int E) {
    int e = blockIdx.x * 256 + threadIdx.x;
    if (e < E) {
        int r = row[e], c = col[e];
        int pos = rowptr[c] + atomicAdd(&fill[c], 1);
        csr_src[pos] = r;
        csr_norm[pos] = dis[r] * w[e] * dis[c];
    }
}

// ---------------- GEMM1: x[N,512] @ W1[512,128] -> h1[N,128] (fp32) ----------------
#define G1_BM 64
#define G1_BK 16
__global__ __launch_bounds__(256) void gemm1(const float* __restrict__ x,
                                             const float* __restrict__ W,
                                             float* __restrict__ h, int N) {
    __shared__ float sA[G1_BK][G1_BM + 1];   // transposed A tile, +1 pad
    __shared__ float sB[G1_BK][NHID];
    int row0 = blockIdx.x * G1_BM;
    int tid = threadIdx.x;
    int tr = tid >> 4;        // 0..15 -> 4 rows each
    int tc = tid & 15;        // 0..15 -> 8 cols each
    float acc[4][8];
#pragma unroll
    for (int i = 0; i < 4; i++)
#pragma unroll
        for (int j = 0; j < 8; j++) acc[i][j] = 0.f;

    int kk  = tid & 15;       // A-load k index
    int rr0 = tid >> 4;       // A-load row base
    int c   = tid & 127;      // B-load col
    int kb0 = tid >> 7;       // B-load k base (0..1)

    for (int k0 = 0; k0 < NFEAT; k0 += G1_BK) {
#pragma unroll
        for (int it = 0; it < 4; it++) {
            int r = rr0 + it * 16;
            int gr = row0 + r;
            sA[kk][r] = (gr < N) ? x[(size_t)gr * NFEAT + k0 + kk] : 0.f;
        }
#pragma unroll
        for (int it = 0; it < 8; it++) {
            int kbb = kb0 + it * 2;
            sB[kbb][c] = W[(size_t)(k0 + kbb) * NHID + c];
        }
        __syncthreads();
#pragma unroll
        for (int k = 0; k < G1_BK; k++) {
            float a[4], bb[8];
#pragma unroll
            for (int i = 0; i < 4; i++) a[i] = sA[k][tr * 4 + i];
#pragma unroll
            for (int j = 0; j < 8; j++) bb[j] = sB[k][tc * 8 + j];
#pragma unroll
            for (int i = 0; i < 4; i++)
#pragma unroll
                for (int j = 0; j < 8; j++) acc[i][j] += a[i] * bb[j];
        }
        __syncthreads();
    }
#pragma unroll
    for (int i = 0; i < 4; i++) {
        int gr = row0 + tr * 4 + i;
        if (gr < N) {
            float4* p = (float4*)&h[(size_t)gr * NHID + tc * 8];
            p[0] = make_float4(acc[i][0], acc[i][1], acc[i][2], acc[i][3]);
            p[1] = make_float4(acc[i][4], acc[i][5], acc[i][6], acc[i][7]);
        }
    }
}

// ---------------- SpMM1: out = A_norm @ h1, + b1, relu -> hrelu ----------------
// 32 lanes per node, float4 per lane (128 feats). 8 nodes per block.
__global__ __launch_bounds__(256) void spmm1(const float* __restrict__ h1,
                                             const int* __restrict__ rowptr,
                                             const int* __restrict__ csr_src,
                                             const float* __restrict__ csr_norm,
                                             const float* __restrict__ dis,
                                             const float* __restrict__ b1,
                                             float* __restrict__ hrelu, int N) {
    int tid = threadIdx.x;
    int node = blockIdx.x * 8 + (tid >> 5);
    int lane = tid & 31;
    if (node >= N) return;
    const float4* hv = (const float4*)h1;
    float d = dis[node];
    float sc = d * d;                       // self-loop norm
    float4 self = hv[(size_t)node * 32 + lane];
    float4 acc = make_float4(sc * self.x, sc * self.y, sc * self.z, sc * self.w);
    int e0 = rowptr[node], e1 = rowptr[node + 1];
    for (int e = e0; e < e1; e++) {
        int s = csr_src[e];
        float nm = csr_norm[e];
        float4 v = hv[(size_t)s * 32 + lane];
        acc.x += nm * v.x; acc.y += nm * v.y;
        acc.z += nm * v.z; acc.w += nm * v.w;
    }
    float4 bb = ((const float4*)b1)[lane];
    acc.x = fmaxf(acc.x + bb.x, 0.f);
    acc.y = fmaxf(acc.y + bb.y, 0.f);
    acc.z = fmaxf(acc.z + bb.z, 0.f);
    acc.w = fmaxf(acc.w + bb.w, 0.f);
    ((float4*)hrelu)[(size_t)node * 32 + lane] = acc;
}

// ---------------- GEMM2: hrelu[N,128] @ W2[128,40] -> h2[N,40] ----------------
__global__ __launch_bounds__(256) void gemm2(const float* __restrict__ h,
                                             const float* __restrict__ W2,
                                             float* __restrict__ out, int N) {
    __shared__ float sH[64][NHID + 1];
    __shared__ float sW[NHID * NCLS];
    int row0 = blockIdx.x * 64;
    int tid = threadIdx.x;
    for (int i = tid; i < NHID * NCLS; i += 256) sW[i] = W2[i];
    for (int i = tid; i < 64 * NHID; i += 256) {
        int r = i >> 7, cc = i & 127;
        int gr = row0 + r;
        sH[r][cc] = (gr < N) ? h[(size_t)gr * NHID + cc] : 0.f;
    }
    __syncthreads();
    int r = tid & 63;
    int c0 = (tid >> 6) * 10;     // 4 groups of 10 cols
    float acc[10];
#pragma unroll
    for (int j = 0; j < 10; j++) acc[j] = 0.f;
    for (int k = 0; k < NHID; k++) {
        float a = sH[r][k];
#pragma unroll
        for (int j = 0; j < 10; j++) acc[j] += a * sW[k * NCLS + c0 + j];
    }
    int gr = row0 + r;
    if (gr < N) {
#pragma unroll
        for (int j = 0; j < 10; j++) out[(size_t)gr * NCLS + c0 + j] = acc[j];
    }
}

// ---------------- SpMM2: out = A_norm @ h2 + b2 ----------------
// 8 lanes per node, 5 feats each (40 total). 32 nodes per block.
__global__ __launch_bounds__(256) void spmm2(const float* __restrict__ h2,
                                             const int* __restrict__ rowptr,
                                             const int* __restrict__ csr_src,
                                             const float* __restrict__ csr_norm,
                                             const float* __restrict__ dis,
                                             const float* __restrict__ b2,
                                             float* __restrict__ out, int N) {
    int tid = threadIdx.x;
    int node = blockIdx.x * 32 + (tid >> 3);
    int g = tid & 7;
    if (node >= N) return;
    int f0 = g * 5;
    float d = dis[node];
    float sc = d * d;
    float acc[5];
#pragma unroll
    for (int j = 0; j < 5; j++) acc[j] = sc * h2[(size_t)node * NCLS + f0 + j];
    int e0 = rowptr[node], e1 = rowptr[node + 1];
    for (int e = e0; e < e1; e++) {
        int s = csr_src[e];
        float nm = csr_norm[e];
#pragma unroll
        for (int j = 0; j < 5; j++) acc[j] += nm * h2[(size_t)s * NCLS + f0 + j];
    }
#pragma unroll
    for (int j = 0; j < 5; j++) out[(size_t)node * NCLS + f0 + j] = acc[j] + b2[f0 + j];
}

extern "C" void kernel_launch(void* const* d_in, const int* in_sizes, int n_in,
                              void* d_out, int out_size, void* d_ws, size_t ws_size,
                              hipStream_t stream) {
    const float* x   = (const float*)d_in[0];
    const int*  eidx = (const int*)d_in[1];
    const float* ew  = (const float*)d_in[2];
    const float* W1  = (const float*)d_in[3];
    const float* b1  = (const float*)d_in[4];
    const float* W2  = (const float*)d_in[5];
    const float* b2  = (const float*)d_in[6];
    float* out = (float*)d_out;

    int N = in_sizes[0] / NFEAT;     // 100000
    int E = in_sizes[2];             // 3200000
    const int* row = eidx;           // sources
    const int* col = eidx + E;       // targets

    // ---- carve workspace (256B aligned) ----
    char* p = (char*)d_ws;
    auto alloc = [&](size_t bytes) {
        char* q = p;
        p += (bytes + 255) & ~(size_t)255;
        return q;
    };
    float* deg      = (float*)alloc((size_t)N * 4);
    float* dis      = (float*)alloc((size_t)N * 4);
    int*   counts   = (int*)  alloc((size_t)N * 4);
    int*   fill     = (int*)  alloc((size_t)N * 4);
    int*   rowptr   = (int*)  alloc((size_t)(N + 1) * 4);
    int*   bsums    = (int*)  alloc(512 * 4);
    int*   csr_src  = (int*)  alloc((size_t)E * 4);
    float* csr_norm = (float*)alloc((size_t)E * 4);
    float* h1       = (float*)alloc((size_t)N * NHID * 4);
    float* hrelu    = (float*)alloc((size_t)N * NHID * 4);
    float* h2       = h1;   // h1 dead after spmm1; reuse for h2

    hipMemsetAsync(deg,    0, (size_t)N * 4, stream);
    hipMemsetAsync(counts, 0, (size_t)N * 4, stream);
    hipMemsetAsync(fill,   0, (size_t)N * 4, stream);

    int eb = (E + 255) / 256;
    int nb = (N + 255) / 256;

    edge_deg_count<<<eb, 256, 0, stream>>>(row, col, ew, deg, counts, E);
    dis_kernel<<<nb, 256, 0, stream>>>(deg, dis, N);
    scan_blocks<<<nb, 256, 0, stream>>>(counts, rowptr, bsums, N);
    scan_bsums<<<1, 512, 0, stream>>>(bsums, nb);
    add_offsets<<<nb, 256, 0, stream>>>(rowptr, bsums, N, E);
    scatter_edges<<<eb, 256, 0, stream>>>(row, col, ew, dis, rowptr, fill,
                                          csr_src, csr_norm, E);
    gemm1<<<(N + G1_BM - 1) / G1_BM, 256, 0, stream>>>(x, W1, h1, N);
    spmm1<<<(N + 7) / 8, 256, 0, stream>>>(h1, rowptr, csr_src, csr_norm, dis, b1, hrelu, N);
    gemm2<<<(N + 63) / 64, 256, 0, stream>>>(hrelu, W2, h2, N);
    spmm2<<<(N + 31) / 32, 256, 0, stream>>>(h2, rowptr, csr_src, csr_norm, dis, b2, out, N);
}

// Round 2
// 1199.663 us; speedup vs baseline: 1.2115x; 1.2115x over previous
//
#include <hip/hip_runtime.h>

// GCN: N=100000 nodes, E=3.2M edges, 512 -> 128 (relu) -> 40
// Pipeline: W1T(bf16) -> deg/norm -> CSR build -> GEMM1(MFMA bf16) ->
//           SpMM1(bf16 gather,+b1,relu) -> GEMM2 -> SpMM2(+b2)

#define NFEAT 512
#define NHID  128
#define NCLS  40

typedef unsigned short ushort_t;
typedef unsigned int uint_t;

// fp32 -> bf16 round-to-nearest-even
__device__ inline ushort_t f2bf(float f) {
    uint_t u = __float_as_uint(f);
    u += 0x7fffu + ((u >> 16) & 1u);
    return (ushort_t)(u >> 16);
}
__device__ inline uint_t pk2(float a, float b) {
    return (uint_t)f2bf(a) | ((uint_t)f2bf(b) << 16);
}
__device__ inline float lo2f(uint_t u) { return __uint_as_float(u << 16); }
__device__ inline float hi2f(uint_t u) { return __uint_as_float(u & 0xffff0000u); }

// ---------------- W1 transpose + cvt: W1[512][128] f32 -> W1T[128][512] bf16 ----------------
__global__ void w1t_kernel(const float* __restrict__ W1, ushort_t* __restrict__ W1T) {
    int idx = blockIdx.x * 256 + threadIdx.x;   // 65536
    int k = idx >> 7, n = idx & 127;
    W1T[n * NFEAT + k] = f2bf(W1[idx]);
}

// ---------------- degree + counts (per-edge atomics) ----------------
__global__ void edge_deg_count(const int* __restrict__ row, const int* __restrict__ col,
                               const float* __restrict__ w,
                               float* __restrict__ deg, int* __restrict__ counts, int E) {
    int e = blockIdx.x * 256 + threadIdx.x;
    if (e < E) {
        int c = col[e];
        atomicAdd(&deg[c], w[e]);
        atomicAdd(&counts[c], 1);
    }
}

__global__ void dis_kernel(const float* __restrict__ deg, float* __restrict__ dis, int N) {
    int i = blockIdx.x * 256 + threadIdx.x;
    if (i < N) dis[i] = rsqrtf(deg[i] + 1.0f);
}

// ---------------- exclusive scan (3 kernels) ----------------
__global__ void scan_blocks(const int* __restrict__ counts, int* __restrict__ rowptr,
                            int* __restrict__ bsums, int N) {
    __shared__ int s[256];
    int tid = threadIdx.x;
    int i = blockIdx.x * 256 + tid;
    int v = (i < N) ? counts[i] : 0;
    s[tid] = v;
    __syncthreads();
    for (int off = 1; off < 256; off <<= 1) {
        int t = (tid >= off) ? s[tid - off] : 0;
        __syncthreads();
        s[tid] += t;
        __syncthreads();
    }
    if (i < N) rowptr[i] = s[tid] - v;
    if (tid == 255) bsums[blockIdx.x] = s[255];
}

__global__ void scan_bsums(int* __restrict__ bsums, int nb) {
    __shared__ int s[512];
    int t = threadIdx.x;
    int v = (t < nb) ? bsums[t] : 0;
    s[t] = v;
    __syncthreads();
    for (int off = 1; off < 512; off <<= 1) {
        int u = (t >= off) ? s[t - off] : 0;
        __syncthreads();
        s[t] += u;
        __syncthreads();
    }
    if (t < nb) bsums[t] = s[t] - v;
}

__global__ void add_offsets(int* __restrict__ rowptr, const int* __restrict__ bsums,
                            int N, int E) {
    int i = blockIdx.x * 256 + threadIdx.x;
    if (i < N) rowptr[i] += bsums[blockIdx.x];
    if (i == 0) rowptr[N] = E;
}

// ---------------- scatter edges into CSR (by dst) ----------------
__global__ void scatter_edges(const int* __restrict__ row, const int* __restrict__ col,
                              const float* __restrict__ w, const float* __restrict__ dis,
                              const int* __restrict__ rowptr, int* __restrict__ fill,
                              int* __restrict__ csr_src, float* __restrict__ csr_norm, int E) {
    int e = blockIdx.x * 256 + threadIdx.x;
    if (e < E) {
        int r = row[e], c = col[e];
        int pos = rowptr[c] + atomicAdd(&fill[c], 1);
        csr_src[pos] = r;
        csr_norm[pos] = dis[r] * w[e] * dis[c];
    }
}

// ---------------- GEMM1 (MFMA): x[N,512]f32 @ W1 -> h1[N,128] bf16 ----------------
// 128x128 block tile, 4 waves in 2x2, each 64x64 via 4x4 of 16x16x32 MFMA.
// A staged fp32->bf16 in LDS (LDA=72 pad); B frags direct from global W1T (bf16).
#define G_BM 128
#define G_BK 64
#define LDA  72

using f32x4  = __attribute__((ext_vector_type(4))) float;
using s16x8  = __attribute__((ext_vector_type(8))) short;

__global__ __launch_bounds__(256) void gemm1_mfma(const float* __restrict__ x,
                                                  const ushort_t* __restrict__ W1T,
                                                  ushort_t* __restrict__ h1, int N) {
    __shared__ ushort_t sA[G_BM * LDA];    // 18432 B
    int tid = threadIdx.x;
    int row0 = blockIdx.x * G_BM;
    int wave = tid >> 6, lane = tid & 63;
    int wm = wave >> 1, wn = wave & 1;
    int lm = lane & 15, quad = lane >> 4;

    f32x4 acc[4][4] = {};

    // staging: thread t handles row sr = t>>1, k-half sk = (t&1)*32
    int sr = tid >> 1;
    int sk = (tid & 1) * 32;
    int gr_st = row0 + sr;
    bool rvalid = gr_st < N;
    const float* xrow = x + (size_t)(rvalid ? gr_st : row0) * NFEAT;

    for (int k0 = 0; k0 < NFEAT; k0 += G_BK) {
        const float4* xv = (const float4*)(xrow + k0 + sk);
#pragma unroll
        for (int q = 0; q < 4; q++) {
            float4 a = xv[2 * q];
            float4 b = xv[2 * q + 1];
            if (!rvalid) { a = make_float4(0,0,0,0); b = make_float4(0,0,0,0); }
            uint4 pk;
            pk.x = pk2(a.x, a.y);
            pk.y = pk2(a.z, a.w);
            pk.z = pk2(b.x, b.y);
            pk.w = pk2(b.z, b.w);
            *(uint4*)&sA[sr * LDA + sk + q * 8] = pk;
        }
        __syncthreads();
#pragma unroll
        for (int kk = 0; kk < G_BK; kk += 32) {
            s16x8 af[4], bf[4];
#pragma unroll
            for (int i = 0; i < 4; i++) {
                int m = wm * 64 + i * 16 + lm;
                af[i] = *(const s16x8*)&sA[m * LDA + kk + quad * 8];
            }
#pragma unroll
            for (int j = 0; j < 4; j++) {
                int n = wn * 64 + j * 16 + lm;
                bf[j] = *(const s16x8*)&W1T[(size_t)n * NFEAT + k0 + kk + quad * 8];
            }
#pragma unroll
            for (int i = 0; i < 4; i++)
#pragma unroll
                for (int j = 0; j < 4; j++)
                    acc[i][j] = __builtin_amdgcn_mfma_f32_16x16x32_bf16(af[i], bf[j], acc[i][j], 0, 0, 0);
        }
        __syncthreads();
    }

    // epilogue: D[row=quad*4+r][col=lm] per 16x16 tile -> h1 bf16
#pragma unroll
    for (int i = 0; i < 4; i++) {
        int rbase = row0 + wm * 64 + i * 16 + quad * 4;
#pragma unroll
        for (int r = 0; r < 4; r++) {
            int gr = rbase + r;
            if (gr < N) {
#pragma unroll
                for (int j = 0; j < 4; j++) {
                    int colx = wn * 64 + j * 16 + lm;
                    h1[(size_t)gr * NHID + colx] = f2bf(acc[i][j][r]);
                }
            }
        }
    }
}

// ---------------- SpMM1: hrelu = relu(A_norm @ h1 + b1), bf16 in/out ----------------
// 32 lanes per node, uint2 (4 bf16) per lane. 8 nodes per block.
__global__ __launch_bounds__(256) void spmm1(const ushort_t* __restrict__ h1,
                                             const int* __restrict__ rowptr,
                                             const int* __restrict__ csr_src,
                                             const float* __restrict__ csr_norm,
                                             const float* __restrict__ dis,
                                             const float* __restrict__ b1,
                                             ushort_t* __restrict__ hrelu, int N) {
    int tid = threadIdx.x;
    int node = blockIdx.x * 8 + (tid >> 5);
    int lane = tid & 31;
    if (node >= N) return;
    const uint2* hv = (const uint2*)h1;   // 32 uint2 per node row
    float d = dis[node];
    float sc = d * d;
    uint2 sv = hv[(size_t)node * 32 + lane];
    float a0 = sc * lo2f(sv.x), a1 = sc * hi2f(sv.x);
    float a2 = sc * lo2f(sv.y), a3 = sc * hi2f(sv.y);
    int e0 = rowptr[node], e1 = rowptr[node + 1];
    for (int e = e0; e < e1; e++) {
        int s = csr_src[e];
        float nm = csr_norm[e];
        uint2 v = hv[(size_t)s * 32 + lane];
        a0 += nm * lo2f(v.x); a1 += nm * hi2f(v.x);
        a2 += nm * lo2f(v.y); a3 += nm * hi2f(v.y);
    }
    const float4 bb = ((const float4*)b1)[lane];
    a0 = fmaxf(a0 + bb.x, 0.f);
    a1 = fmaxf(a1 + bb.y, 0.f);
    a2 = fmaxf(a2 + bb.z, 0.f);
    a3 = fmaxf(a3 + bb.w, 0.f);
    uint2 o;
    o.x = pk2(a0, a1);
    o.y = pk2(a2, a3);
    ((uint2*)hrelu)[(size_t)node * 32 + lane] = o;
}

// ---------------- GEMM2: hrelu[N,128]bf16 @ W2[128,40] -> h2[N,40] f32 ----------------
__global__ __launch_bounds__(256) void gemm2(const ushort_t* __restrict__ h,
                                             const float* __restrict__ W2,
                                             float* __restrict__ out, int N) {
    __shared__ float sH[64][NHID + 1];
    __shared__ float sW[NHID * NCLS];
    int row0 = blockIdx.x * 64;
    int tid = threadIdx.x;
    for (int i = tid; i < NHID * NCLS; i += 256) sW[i] = W2[i];
    const uint2* hv = (const uint2*)h;
    for (int i = tid; i < 64 * 32; i += 256) {   // uint2 units: 4 feats each
        int r = i >> 5, c4 = (i & 31) * 4;
        int gr = row0 + r;
        uint2 v = (gr < N) ? hv[(size_t)gr * 32 + (i & 31)] : make_uint2(0, 0);
        sH[r][c4 + 0] = lo2f(v.x);
        sH[r][c4 + 1] = hi2f(v.x);
        sH[r][c4 + 2] = lo2f(v.y);
        sH[r][c4 + 3] = hi2f(v.y);
    }
    __syncthreads();
    int r = tid & 63;
    int c0 = (tid >> 6) * 10;
    float acc[10];
#pragma unroll
    for (int j = 0; j < 10; j++) acc[j] = 0.f;
    for (int k = 0; k < NHID; k++) {
        float a = sH[r][k];
#pragma unroll
        for (int j = 0; j < 10; j++) acc[j] += a * sW[k * NCLS + c0 + j];
    }
    int gr = row0 + r;
    if (gr < N) {
#pragma unroll
        for (int j = 0; j < 10; j++) out[(size_t)gr * NCLS + c0 + j] = acc[j];
    }
}

// ---------------- SpMM2: out = A_norm @ h2 + b2 ----------------
__global__ __launch_bounds__(256) void spmm2(const float* __restrict__ h2,
                                             const int* __restrict__ rowptr,
                                             const int* __restrict__ csr_src,
                                             const float* __restrict__ csr_norm,
                                             const float* __restrict__ dis,
                                             const float* __restrict__ b2,
                                             float* __restrict__ out, int N) {
    int tid = threadIdx.x;
    int node = blockIdx.x * 32 + (tid >> 3);
    int g = tid & 7;
    if (node >= N) return;
    int f0 = g * 5;
    float d = dis[node];
    float sc = d * d;
    float acc[5];
#pragma unroll
    for (int j = 0; j < 5; j++) acc[j] = sc * h2[(size_t)node * NCLS + f0 + j];
    int e0 = rowptr[node], e1 = rowptr[node + 1];
    for (int e = e0; e < e1; e++) {
        int s = csr_src[e];
        float nm = csr_norm[e];
#pragma unroll
        for (int j = 0; j < 5; j++) acc[j] += nm * h2[(size_t)s * NCLS + f0 + j];
    }
#pragma unroll
    for (int j = 0; j < 5; j++) out[(size_t)node * NCLS + f0 + j] = acc[j] + b2[f0 + j];
}

extern "C" void kernel_launch(void* const* d_in, const int* in_sizes, int n_in,
                              void* d_out, int out_size, void* d_ws, size_t ws_size,
                              hipStream_t stream) {
    const float* x   = (const float*)d_in[0];
    const int*  eidx = (const int*)d_in[1];
    const float* ew  = (const float*)d_in[2];
    const float* W1  = (const float*)d_in[3];
    const float* b1  = (const float*)d_in[4];
    const float* W2  = (const float*)d_in[5];
    const float* b2  = (const float*)d_in[6];
    float* out = (float*)d_out;

    int N = in_sizes[0] / NFEAT;     // 100000
    int E = in_sizes[2];             // 3200000
    const int* row = eidx;
    const int* col = eidx + E;

    char* p = (char*)d_ws;
    auto alloc = [&](size_t bytes) {
        char* q = p;
        p += (bytes + 255) & ~(size_t)255;
        return q;
    };
    float*    deg      = (float*)   alloc((size_t)N * 4);
    float*    dis      = (float*)   alloc((size_t)N * 4);
    int*      counts   = (int*)     alloc((size_t)N * 4);
    int*      fill     = (int*)     alloc((size_t)N * 4);
    int*      rowptr   = (int*)     alloc((size_t)(N + 1) * 4);
    int*      bsums    = (int*)     alloc(512 * 4);
    int*      csr_src  = (int*)     alloc((size_t)E * 4);
    float*    csr_norm = (float*)   alloc((size_t)E * 4);
    ushort_t* W1T      = (ushort_t*)alloc((size_t)NFEAT * NHID * 2);
    ushort_t* h1       = (ushort_t*)alloc((size_t)N * NHID * 2);
    ushort_t* hrelu    = (ushort_t*)alloc((size_t)N * NHID * 2);
    float*    h2       = (float*)   alloc((size_t)N * NCLS * 4);

    hipMemsetAsync(deg,    0, (size_t)N * 4, stream);
    hipMemsetAsync(counts, 0, (size_t)N * 4, stream);
    hipMemsetAsync(fill,   0, (size_t)N * 4, stream);

    int eb = (E + 255) / 256;
    int nb = (N + 255) / 256;

    w1t_kernel<<<(NFEAT * NHID) / 256, 256, 0, stream>>>(W1, W1T);
    edge_deg_count<<<eb, 256, 0, stream>>>(row, col, ew, deg, counts, E);
    dis_kernel<<<nb, 256, 0, stream>>>(deg, dis, N);
    scan_blocks<<<nb, 256, 0, stream>>>(counts, rowptr, bsums, N);
    scan_bsums<<<1, 512, 0, stream>>>(bsums, nb);
    add_offsets<<<nb, 256, 0, stream>>>(rowptr, bsums, N, E);
    scatter_edges<<<eb, 256, 0, stream>>>(row, col, ew, dis, rowptr, fill,
                                          csr_src, csr_norm, E);
    gemm1_mfma<<<(N + G_BM - 1) / G_BM, 256, 0, stream>>>(x, W1T, h1, N);
    spmm1<<<(N + 7) / 8, 256, 0, stream>>>(h1, rowptr, csr_src, csr_norm, dis, b1, hrelu, N);
    gemm2<<<(N + 63) / 64, 256, 0, stream>>>(hrelu, W2, h2, N);
    spmm2<<<(N + 31) / 32, 256, 0, stream>>>(h2, rowptr, csr_src, csr_norm, dis, b2, out, N);
}

// Round 3
// 875.137 us; speedup vs baseline: 1.6608x; 1.3708x over previous
//
#include <hip/hip_runtime.h>

// GCN: N=100000 nodes, E=3.2M edges, 512 -> 128 (relu) -> 40
// Pipeline: W1T(bf16) -> edge rank+deg (single 64b atomic/edge) -> scan ->
//           atomic-free scatter -> GEMM1(MFMA bf16) -> SpMM1 -> GEMM2 -> SpMM2

#define NFEAT 512
#define NHID  128
#define NCLS  40

typedef unsigned short ushort_t;
typedef unsigned int uint_t;
typedef unsigned long long ull_t;

#define WSCALE 2097152.0f          // 2^21 fixed-point scale for weight sums
#define WINV   (1.0f / 2097152.0f)

// fp32 -> bf16 round-to-nearest-even
__device__ inline ushort_t f2bf(float f) {
    uint_t u = __float_as_uint(f);
    u += 0x7fffu + ((u >> 16) & 1u);
    return (ushort_t)(u >> 16);
}
__device__ inline uint_t pk2(float a, float b) {
    return (uint_t)f2bf(a) | ((uint_t)f2bf(b) << 16);
}
__device__ inline float lo2f(uint_t u) { return __uint_as_float(u << 16); }
__device__ inline float hi2f(uint_t u) { return __uint_as_float(u & 0xffff0000u); }

// ---------------- W1 transpose + cvt: W1[512][128] f32 -> W1T[128][512] bf16 ----------------
__global__ void w1t_kernel(const float* __restrict__ W1, ushort_t* __restrict__ W1T) {
    int idx = blockIdx.x * 256 + threadIdx.x;   // 65536
    int k = idx >> 7, n = idx & 127;
    W1T[n * NFEAT + k] = f2bf(W1[idx]);
}

// ---------------- pass A: one 64-bit atomic per edge; rank from return ----------------
// degcnt[c] = (count << 32) | fixedpoint_weight_sum
__global__ void edge_rank_deg(const int* __restrict__ col, const float* __restrict__ w,
                              ull_t* __restrict__ degcnt, int* __restrict__ rank, int E) {
    int e = blockIdx.x * 256 + threadIdx.x;
    if (e < E) {
        ull_t pk = (1ULL << 32) | (ull_t)__float2uint_rn(w[e] * WSCALE);
        ull_t old = atomicAdd(&degcnt[col[e]], pk);
        rank[e] = (int)(old >> 32);
    }
}

__global__ void dis_kernel(const ull_t* __restrict__ degcnt, float* __restrict__ dis, int N) {
    int i = blockIdx.x * 256 + threadIdx.x;
    if (i < N) {
        float deg = (float)(uint_t)degcnt[i] * WINV;
        dis[i] = rsqrtf(deg + 1.0f);    // +1 = self-loop weight
    }
}

// ---------------- exclusive scan over counts (high word of degcnt) ----------------
__global__ void scan_blocks(const ull_t* __restrict__ degcnt, int* __restrict__ rowptr,
                            int* __restrict__ bsums, int N) {
    __shared__ int s[256];
    int tid = threadIdx.x;
    int i = blockIdx.x * 256 + tid;
    int v = (i < N) ? (int)(degcnt[i] >> 32) : 0;
    s[tid] = v;
    __syncthreads();
    for (int off = 1; off < 256; off <<= 1) {
        int t = (tid >= off) ? s[tid - off] : 0;
        __syncthreads();
        s[tid] += t;
        __syncthreads();
    }
    if (i < N) rowptr[i] = s[tid] - v;
    if (tid == 255) bsums[blockIdx.x] = s[255];
}

__global__ void scan_bsums(int* __restrict__ bsums, int nb) {
    __shared__ int s[512];
    int t = threadIdx.x;
    int v = (t < nb) ? bsums[t] : 0;
    s[t] = v;
    __syncthreads();
    for (int off = 1; off < 512; off <<= 1) {
        int u = (t >= off) ? s[t - off] : 0;
        __syncthreads();
        s[t] += u;
        __syncthreads();
    }
    if (t < nb) bsums[t] = s[t] - v;
}

__global__ void add_offsets(int* __restrict__ rowptr, const int* __restrict__ bsums,
                            int N, int E) {
    int i = blockIdx.x * 256 + threadIdx.x;
    if (i < N) rowptr[i] += bsums[blockIdx.x];
    if (i == 0) rowptr[N] = E;
}

// ---------------- pass B: atomic-free scatter into interleaved CSR ----------------
__global__ void scatter_edges(const int* __restrict__ row, const int* __restrict__ col,
                              const float* __restrict__ w, const int* __restrict__ rank,
                              const int* __restrict__ rowptr, const float* __restrict__ dis,
                              int2* __restrict__ csr, int E) {
    int e = blockIdx.x * 256 + threadIdx.x;
    if (e < E) {
        int r = row[e], c = col[e];
        int pos = rowptr[c] + rank[e];
        float nm = dis[r] * w[e] * dis[c];
        csr[pos] = make_int2(r, __float_as_int(nm));
    }
}

// ---------------- GEMM1 (MFMA): x[N,512]f32 @ W1 -> h1[N,128] bf16 ----------------
#define G_BM 128
#define G_BK 64
#define LDA  72

using f32x4  = __attribute__((ext_vector_type(4))) float;
using s16x8  = __attribute__((ext_vector_type(8))) short;

__global__ __launch_bounds__(256) void gemm1_mfma(const float* __restrict__ x,
                                                  const ushort_t* __restrict__ W1T,
                                                  ushort_t* __restrict__ h1, int N) {
    __shared__ ushort_t sA[G_BM * LDA];    // 18432 B
    int tid = threadIdx.x;
    int row0 = blockIdx.x * G_BM;
    int wave = tid >> 6, lane = tid & 63;
    int wm = wave >> 1, wn = wave & 1;
    int lm = lane & 15, quad = lane >> 4;

    f32x4 acc[4][4] = {};

    int sr = tid >> 1;
    int sk = (tid & 1) * 32;
    int gr_st = row0 + sr;
    bool rvalid = gr_st < N;
    const float* xrow = x + (size_t)(rvalid ? gr_st : row0) * NFEAT;

    for (int k0 = 0; k0 < NFEAT; k0 += G_BK) {
        const float4* xv = (const float4*)(xrow + k0 + sk);
#pragma unroll
        for (int q = 0; q < 4; q++) {
            float4 a = xv[2 * q];
            float4 b = xv[2 * q + 1];
            if (!rvalid) { a = make_float4(0,0,0,0); b = make_float4(0,0,0,0); }
            uint4 pk;
            pk.x = pk2(a.x, a.y);
            pk.y = pk2(a.z, a.w);
            pk.z = pk2(b.x, b.y);
            pk.w = pk2(b.z, b.w);
            *(uint4*)&sA[sr * LDA + sk + q * 8] = pk;
        }
        __syncthreads();
#pragma unroll
        for (int kk = 0; kk < G_BK; kk += 32) {
            s16x8 af[4], bf[4];
#pragma unroll
            for (int i = 0; i < 4; i++) {
                int m = wm * 64 + i * 16 + lm;
                af[i] = *(const s16x8*)&sA[m * LDA + kk + quad * 8];
            }
#pragma unroll
            for (int j = 0; j < 4; j++) {
                int n = wn * 64 + j * 16 + lm;
                bf[j] = *(const s16x8*)&W1T[(size_t)n * NFEAT + k0 + kk + quad * 8];
            }
#pragma unroll
            for (int i = 0; i < 4; i++)
#pragma unroll
                for (int j = 0; j < 4; j++)
                    acc[i][j] = __builtin_amdgcn_mfma_f32_16x16x32_bf16(af[i], bf[j], acc[i][j], 0, 0, 0);
        }
        __syncthreads();
    }

#pragma unroll
    for (int i = 0; i < 4; i++) {
        int rbase = row0 + wm * 64 + i * 16 + quad * 4;
#pragma unroll
        for (int r = 0; r < 4; r++) {
            int gr = rbase + r;
            if (gr < N) {
#pragma unroll
                for (int j = 0; j < 4; j++) {
                    int colx = wn * 64 + j * 16 + lm;
                    h1[(size_t)gr * NHID + colx] = f2bf(acc[i][j][r]);
                }
            }
        }
    }
}

// ---------------- SpMM1: hrelu = relu(A_norm @ h1 + b1), bf16 in/out ----------------
// 32 lanes per node, uint2 (4 bf16) per lane. 8 nodes per block. 2x edge unroll.
__global__ __launch_bounds__(256) void spmm1(const ushort_t* __restrict__ h1,
                                             const int* __restrict__ rowptr,
                                             const int2* __restrict__ csr,
                                             const float* __restrict__ dis,
                                             const float* __restrict__ b1,
                                             ushort_t* __restrict__ hrelu, int N) {
    int tid = threadIdx.x;
    int node = blockIdx.x * 8 + (tid >> 5);
    int lane = tid & 31;
    if (node >= N) return;
    const uint2* hv = (const uint2*)h1;
    float d = dis[node];
    float sc = d * d;
    uint2 sv = hv[(size_t)node * 32 + lane];
    float a0 = sc * lo2f(sv.x), a1 = sc * hi2f(sv.x);
    float a2 = sc * lo2f(sv.y), a3 = sc * hi2f(sv.y);
    int e0 = rowptr[node], e1 = rowptr[node + 1];
    int e = e0;
    for (; e + 1 < e1; e += 2) {
        int2 c0 = csr[e];
        int2 c1 = csr[e + 1];
        uint2 v0 = hv[(size_t)c0.x * 32 + lane];
        uint2 v1 = hv[(size_t)c1.x * 32 + lane];
        float n0 = __int_as_float(c0.y);
        float n1 = __int_as_float(c1.y);
        a0 += n0 * lo2f(v0.x); a1 += n0 * hi2f(v0.x);
        a2 += n0 * lo2f(v0.y); a3 += n0 * hi2f(v0.y);
        a0 += n1 * lo2f(v1.x); a1 += n1 * hi2f(v1.x);
        a2 += n1 * lo2f(v1.y); a3 += n1 * hi2f(v1.y);
    }
    if (e < e1) {
        int2 c0 = csr[e];
        uint2 v0 = hv[(size_t)c0.x * 32 + lane];
        float n0 = __int_as_float(c0.y);
        a0 += n0 * lo2f(v0.x); a1 += n0 * hi2f(v0.x);
        a2 += n0 * lo2f(v0.y); a3 += n0 * hi2f(v0.y);
    }
    const float4 bb = ((const float4*)b1)[lane];
    a0 = fmaxf(a0 + bb.x, 0.f);
    a1 = fmaxf(a1 + bb.y, 0.f);
    a2 = fmaxf(a2 + bb.z, 0.f);
    a3 = fmaxf(a3 + bb.w, 0.f);
    uint2 o;
    o.x = pk2(a0, a1);
    o.y = pk2(a2, a3);
    ((uint2*)hrelu)[(size_t)node * 32 + lane] = o;
}

// ---------------- GEMM2: hrelu[N,128]bf16 @ W2[128,40] -> h2[N,40] f32 ----------------
__global__ __launch_bounds__(256) void gemm2(const ushort_t* __restrict__ h,
                                             const float* __restrict__ W2,
                                             float* __restrict__ out, int N) {
    __shared__ float sH[64][NHID + 1];
    __shared__ float sW[NHID * NCLS];
    int row0 = blockIdx.x * 64;
    int tid = threadIdx.x;
    for (int i = tid; i < NHID * NCLS; i += 256) sW[i] = W2[i];
    const uint2* hv = (const uint2*)h;
    for (int i = tid; i < 64 * 32; i += 256) {
        int r = i >> 5, c4 = (i & 31) * 4;
        int gr = row0 + r;
        uint2 v = (gr < N) ? hv[(size_t)gr * 32 + (i & 31)] : make_uint2(0, 0);
        sH[r][c4 + 0] = lo2f(v.x);
        sH[r][c4 + 1] = hi2f(v.x);
        sH[r][c4 + 2] = lo2f(v.y);
        sH[r][c4 + 3] = hi2f(v.y);
    }
    __syncthreads();
    int r = tid & 63;
    int c0 = (tid >> 6) * 10;
    float acc[10];
#pragma unroll
    for (int j = 0; j < 10; j++) acc[j] = 0.f;
    for (int k = 0; k < NHID; k++) {
        float a = sH[r][k];
#pragma unroll
        for (int j = 0; j < 10; j++) acc[j] += a * sW[k * NCLS + c0 + j];
    }
    int gr = row0 + r;
    if (gr < N) {
#pragma unroll
        for (int j = 0; j < 10; j++) out[(size_t)gr * NCLS + c0 + j] = acc[j];
    }
}

// ---------------- SpMM2: out = A_norm @ h2 + b2 ----------------
__global__ __launch_bounds__(256) void spmm2(const float* __restrict__ h2,
                                             const int* __restrict__ rowptr,
                                             const int2* __restrict__ csr,
                                             const float* __restrict__ dis,
                                             const float* __restrict__ b2,
                                             float* __restrict__ out, int N) {
    int tid = threadIdx.x;
    int node = blockIdx.x * 32 + (tid >> 3);
    int g = tid & 7;
    if (node >= N) return;
    int f0 = g * 5;
    float d = dis[node];
    float sc = d * d;
    float acc[5];
#pragma unroll
    for (int j = 0; j < 5; j++) acc[j] = sc * h2[(size_t)node * NCLS + f0 + j];
    int e0 = rowptr[node], e1 = rowptr[node + 1];
    for (int e = e0; e < e1; e++) {
        int2 c0 = csr[e];
        float nm = __int_as_float(c0.y);
#pragma unroll
        for (int j = 0; j < 5; j++) acc[j] += nm * h2[(size_t)c0.x * NCLS + f0 + j];
    }
#pragma unroll
    for (int j = 0; j < 5; j++) out[(size_t)node * NCLS + f0 + j] = acc[j] + b2[f0 + j];
}

extern "C" void kernel_launch(void* const* d_in, const int* in_sizes, int n_in,
                              void* d_out, int out_size, void* d_ws, size_t ws_size,
                              hipStream_t stream) {
    const float* x   = (const float*)d_in[0];
    const int*  eidx = (const int*)d_in[1];
    const float* ew  = (const float*)d_in[2];
    const float* W1  = (const float*)d_in[3];
    const float* b1  = (const float*)d_in[4];
    const float* W2  = (const float*)d_in[5];
    const float* b2  = (const float*)d_in[6];
    float* out = (float*)d_out;

    int N = in_sizes[0] / NFEAT;     // 100000
    int E = in_sizes[2];             // 3200000
    const int* row = eidx;
    const int* col = eidx + E;

    char* p = (char*)d_ws;
    auto alloc = [&](size_t bytes) {
        char* q = p;
        p += (bytes + 255) & ~(size_t)255;
        return q;
    };
    ull_t*    degcnt   = (ull_t*)   alloc((size_t)N * 8);
    float*    dis      = (float*)   alloc((size_t)N * 4);
    int*      rank     = (int*)     alloc((size_t)E * 4);
    int*      rowptr   = (int*)     alloc((size_t)(N + 1) * 4);
    int*      bsums    = (int*)     alloc(512 * 4);
    int2*     csr      = (int2*)    alloc((size_t)E * 8);
    ushort_t* W1T      = (ushort_t*)alloc((size_t)NFEAT * NHID * 2);
    ushort_t* h1       = (ushort_t*)alloc((size_t)N * NHID * 2);
    ushort_t* hrelu    = (ushort_t*)alloc((size_t)N * NHID * 2);
    float*    h2       = (float*)   alloc((size_t)N * NCLS * 4);

    hipMemsetAsync(degcnt, 0, (size_t)N * 8, stream);

    int eb = (E + 255) / 256;
    int nb = (N + 255) / 256;

    w1t_kernel<<<(NFEAT * NHID) / 256, 256, 0, stream>>>(W1, W1T);
    edge_rank_deg<<<eb, 256, 0, stream>>>(col, ew, degcnt, rank, E);
    dis_kernel<<<nb, 256, 0, stream>>>(degcnt, dis, N);
    scan_blocks<<<nb, 256, 0, stream>>>(degcnt, rowptr, bsums, N);
    scan_bsums<<<1, 512, 0, stream>>>(bsums, nb);
    add_offsets<<<nb, 256, 0, stream>>>(rowptr, bsums, N, E);
    scatter_edges<<<eb, 256, 0, stream>>>(row, col, ew, rank, rowptr, dis, csr, E);
    gemm1_mfma<<<(N + G_BM - 1) / G_BM, 256, 0, stream>>>(x, W1T, h1, N);
    spmm1<<<(N + 7) / 8, 256, 0, stream>>>(h1, rowptr, csr, dis, b1, hrelu, N);
    gemm2<<<(N + 63) / 64, 256, 0, stream>>>(hrelu, W2, h2, N);
    spmm2<<<(N + 31) / 32, 256, 0, stream>>>(h2, rowptr, csr, dis, b2, out, N);
}

// Round 4
// 863.707 us; speedup vs baseline: 1.6828x; 1.0132x over previous
//
#include <hip/hip_runtime.h>

// GCN: N=100000 nodes, E=3.2M edges, 512 -> 128 (relu) -> 40
// Pipeline: W1T(bf16) -> edge rank+deg (64b atomic/edge, 128B-padded) -> scan ->
//           atomic-free scatter -> GEMM1(MFMA bf16) -> SpMM1 -> GEMM2 -> SpMM2

#define NFEAT 512
#define NHID  128
#define NCLS  40
#define DPAD  16        // degcnt stride in ull units: 16*8 = 128 B (one node per L2 line)

typedef unsigned short ushort_t;
typedef unsigned int uint_t;
typedef unsigned long long ull_t;

#define WSCALE 2097152.0f          // 2^21 fixed-point scale for weight sums
#define WINV   (1.0f / 2097152.0f)

// fp32 -> bf16 round-to-nearest-even
__device__ inline ushort_t f2bf(float f) {
    uint_t u = __float_as_uint(f);
    u += 0x7fffu + ((u >> 16) & 1u);
    return (ushort_t)(u >> 16);
}
__device__ inline uint_t pk2(float a, float b) {
    return (uint_t)f2bf(a) | ((uint_t)f2bf(b) << 16);
}
__device__ inline float lo2f(uint_t u) { return __uint_as_float(u << 16); }
__device__ inline float hi2f(uint_t u) { return __uint_as_float(u & 0xffff0000u); }

// ---------------- W1 transpose + cvt: W1[512][128] f32 -> W1T[128][512] bf16 ----------------
__global__ void w1t_kernel(const float* __restrict__ W1, ushort_t* __restrict__ W1T) {
    int idx = blockIdx.x * 256 + threadIdx.x;   // 65536
    int k = idx >> 7, n = idx & 127;
    W1T[n * NFEAT + k] = f2bf(W1[idx]);
}

// ---------------- pass A: one 64-bit atomic per edge; rank from return ----------------
// degcnt[c*DPAD] = (count << 32) | fixedpoint_weight_sum   (128B padded)
__global__ void edge_rank_deg(const int* __restrict__ col, const float* __restrict__ w,
                              ull_t* __restrict__ degcnt, int* __restrict__ rank, int E) {
    int e = blockIdx.x * 256 + threadIdx.x;
    if (e < E) {
        ull_t pk = (1ULL << 32) | (ull_t)__float2uint_rn(w[e] * WSCALE);
        ull_t old = atomicAdd(&degcnt[(size_t)col[e] * DPAD], pk);
        rank[e] = (int)(old >> 32);
    }
}

__global__ void dis_kernel(const ull_t* __restrict__ degcnt, float* __restrict__ dis, int N) {
    int i = blockIdx.x * 256 + threadIdx.x;
    if (i < N) {
        float deg = (float)(uint_t)degcnt[(size_t)i * DPAD] * WINV;
        dis[i] = rsqrtf(deg + 1.0f);    // +1 = self-loop weight
    }
}

// ---------------- exclusive scan over counts (high word of degcnt) ----------------
__global__ void scan_blocks(const ull_t* __restrict__ degcnt, int* __restrict__ rowptr,
                            int* __restrict__ bsums, int N) {
    __shared__ int s[256];
    int tid = threadIdx.x;
    int i = blockIdx.x * 256 + tid;
    int v = (i < N) ? (int)(degcnt[(size_t)i * DPAD] >> 32) : 0;
    s[tid] = v;
    __syncthreads();
    for (int off = 1; off < 256; off <<= 1) {
        int t = (tid >= off) ? s[tid - off] : 0;
        __syncthreads();
        s[tid] += t;
        __syncthreads();
    }
    if (i < N) rowptr[i] = s[tid] - v;
    if (tid == 255) bsums[blockIdx.x] = s[255];
}

__global__ void scan_bsums(int* __restrict__ bsums, int nb) {
    __shared__ int s[512];
    int t = threadIdx.x;
    int v = (t < nb) ? bsums[t] : 0;
    s[t] = v;
    __syncthreads();
    for (int off = 1; off < 512; off <<= 1) {
        int u = (t >= off) ? s[t - off] : 0;
        __syncthreads();
        s[t] += u;
        __syncthreads();
    }
    if (t < nb) bsums[t] = s[t] - v;
}

__global__ void add_offsets(int* __restrict__ rowptr, const int* __restrict__ bsums,
                            int N, int E) {
    int i = blockIdx.x * 256 + threadIdx.x;
    if (i < N) rowptr[i] += bsums[blockIdx.x];
    if (i == 0) rowptr[N] = E;
}

// ---------------- pass B: atomic-free scatter into interleaved CSR ----------------
__global__ void scatter_edges(const int* __restrict__ row, const int* __restrict__ col,
                              const float* __restrict__ w, const int* __restrict__ rank,
                              const int* __restrict__ rowptr, const float* __restrict__ dis,
                              int2* __restrict__ csr, int E) {
    int e = blockIdx.x * 256 + threadIdx.x;
    if (e < E) {
        int r = row[e], c = col[e];
        int pos = rowptr[c] + rank[e];
        float nm = dis[r] * w[e] * dis[c];
        csr[pos] = make_int2(r, __float_as_int(nm));
    }
}

// ---------------- GEMM1 (MFMA): x[N,512]f32 @ W1 -> h1[N,128] bf16 ----------------
#define G_BM 128
#define G_BK 64
#define LDA  72

using f32x4  = __attribute__((ext_vector_type(4))) float;
using s16x8  = __attribute__((ext_vector_type(8))) short;

__global__ __launch_bounds__(256) void gemm1_mfma(const float* __restrict__ x,
                                                  const ushort_t* __restrict__ W1T,
                                                  ushort_t* __restrict__ h1, int N) {
    __shared__ ushort_t sA[G_BM * LDA];    // 18432 B
    int tid = threadIdx.x;
    int row0 = blockIdx.x * G_BM;
    int wave = tid >> 6, lane = tid & 63;
    int wm = wave >> 1, wn = wave & 1;
    int lm = lane & 15, quad = lane >> 4;

    f32x4 acc[4][4] = {};

    int sr = tid >> 1;
    int sk = (tid & 1) * 32;
    int gr_st = row0 + sr;
    bool rvalid = gr_st < N;
    const float* xrow = x + (size_t)(rvalid ? gr_st : row0) * NFEAT;

    for (int k0 = 0; k0 < NFEAT; k0 += G_BK) {
        const float4* xv = (const float4*)(xrow + k0 + sk);
#pragma unroll
        for (int q = 0; q < 4; q++) {
            float4 a = xv[2 * q];
            float4 b = xv[2 * q + 1];
            if (!rvalid) { a = make_float4(0,0,0,0); b = make_float4(0,0,0,0); }
            uint4 pk;
            pk.x = pk2(a.x, a.y);
            pk.y = pk2(a.z, a.w);
            pk.z = pk2(b.x, b.y);
            pk.w = pk2(b.z, b.w);
            *(uint4*)&sA[sr * LDA + sk + q * 8] = pk;
        }
        __syncthreads();
#pragma unroll
        for (int kk = 0; kk < G_BK; kk += 32) {
            s16x8 af[4], bf[4];
#pragma unroll
            for (int i = 0; i < 4; i++) {
                int m = wm * 64 + i * 16 + lm;
                af[i] = *(const s16x8*)&sA[m * LDA + kk + quad * 8];
            }
#pragma unroll
            for (int j = 0; j < 4; j++) {
                int n = wn * 64 + j * 16 + lm;
                bf[j] = *(const s16x8*)&W1T[(size_t)n * NFEAT + k0 + kk + quad * 8];
            }
#pragma unroll
            for (int i = 0; i < 4; i++)
#pragma unroll
                for (int j = 0; j < 4; j++)
                    acc[i][j] = __builtin_amdgcn_mfma_f32_16x16x32_bf16(af[i], bf[j], acc[i][j], 0, 0, 0);
        }
        __syncthreads();
    }

#pragma unroll
    for (int i = 0; i < 4; i++) {
        int rbase = row0 + wm * 64 + i * 16 + quad * 4;
#pragma unroll
        for (int r = 0; r < 4; r++) {
            int gr = rbase + r;
            if (gr < N) {
#pragma unroll
                for (int j = 0; j < 4; j++) {
                    int colx = wn * 64 + j * 16 + lm;
                    h1[(size_t)gr * NHID + colx] = f2bf(acc[i][j][r]);
                }
            }
        }
    }
}

// ---------------- SpMM1: hrelu = relu(A_norm @ h1 + b1), bf16 in/out ----------------
// 32 lanes per node, uint2 (4 bf16) per lane. 8 nodes per block. 4x edge unroll (MLP).
__global__ __launch_bounds__(256) void spmm1(const ushort_t* __restrict__ h1,
                                             const int* __restrict__ rowptr,
                                             const int2* __restrict__ csr,
                                             const float* __restrict__ dis,
                                             const float* __restrict__ b1,
                                             ushort_t* __restrict__ hrelu, int N) {
    int tid = threadIdx.x;
    int node = blockIdx.x * 8 + (tid >> 5);
    int lane = tid & 31;
    if (node >= N) return;
    const uint2* hv = (const uint2*)h1;
    float d = dis[node];
    float sc = d * d;
    uint2 sv = hv[(size_t)node * 32 + lane];
    float a0 = sc * lo2f(sv.x), a1 = sc * hi2f(sv.x);
    float a2 = sc * lo2f(sv.y), a3 = sc * hi2f(sv.y);
    int e0 = rowptr[node], e1 = rowptr[node + 1];
    int e = e0;
    for (; e + 3 < e1; e += 4) {
        int2 c0 = csr[e],     c1 = csr[e + 1];
        int2 c2 = csr[e + 2], c3 = csr[e + 3];
        uint2 v0 = hv[(size_t)c0.x * 32 + lane];
        uint2 v1 = hv[(size_t)c1.x * 32 + lane];
        uint2 v2 = hv[(size_t)c2.x * 32 + lane];
        uint2 v3 = hv[(size_t)c3.x * 32 + lane];
        float n0 = __int_as_float(c0.y), n1 = __int_as_float(c1.y);
        float n2 = __int_as_float(c2.y), n3 = __int_as_float(c3.y);
        a0 += n0 * lo2f(v0.x); a1 += n0 * hi2f(v0.x);
        a2 += n0 * lo2f(v0.y); a3 += n0 * hi2f(v0.y);
        a0 += n1 * lo2f(v1.x); a1 += n1 * hi2f(v1.x);
        a2 += n1 * lo2f(v1.y); a3 += n1 * hi2f(v1.y);
        a0 += n2 * lo2f(v2.x); a1 += n2 * hi2f(v2.x);
        a2 += n2 * lo2f(v2.y); a3 += n2 * hi2f(v2.y);
        a0 += n3 * lo2f(v3.x); a1 += n3 * hi2f(v3.x);
        a2 += n3 * lo2f(v3.y); a3 += n3 * hi2f(v3.y);
    }
    for (; e < e1; e++) {
        int2 c0 = csr[e];
        uint2 v0 = hv[(size_t)c0.x * 32 + lane];
        float n0 = __int_as_float(c0.y);
        a0 += n0 * lo2f(v0.x); a1 += n0 * hi2f(v0.x);
        a2 += n0 * lo2f(v0.y); a3 += n0 * hi2f(v0.y);
    }
    const float4 bb = ((const float4*)b1)[lane];
    a0 = fmaxf(a0 + bb.x, 0.f);
    a1 = fmaxf(a1 + bb.y, 0.f);
    a2 = fmaxf(a2 + bb.z, 0.f);
    a3 = fmaxf(a3 + bb.w, 0.f);
    uint2 o;
    o.x = pk2(a0, a1);
    o.y = pk2(a2, a3);
    ((uint2*)hrelu)[(size_t)node * 32 + lane] = o;
}

// ---------------- GEMM2: hrelu[N,128]bf16 @ W2[128,40] -> h2[N,40] f32 ----------------
__global__ __launch_bounds__(256) void gemm2(const ushort_t* __restrict__ h,
                                             const float* __restrict__ W2,
                                             float* __restrict__ out, int N) {
    __shared__ float sH[64][NHID + 1];
    __shared__ float sW[NHID * NCLS];
    int row0 = blockIdx.x * 64;
    int tid = threadIdx.x;
    for (int i = tid; i < NHID * NCLS; i += 256) sW[i] = W2[i];
    const uint2* hv = (const uint2*)h;
    for (int i = tid; i < 64 * 32; i += 256) {
        int r = i >> 5, c4 = (i & 31) * 4;
        int gr = row0 + r;
        uint2 v = (gr < N) ? hv[(size_t)gr * 32 + (i & 31)] : make_uint2(0, 0);
        sH[r][c4 + 0] = lo2f(v.x);
        sH[r][c4 + 1] = hi2f(v.x);
        sH[r][c4 + 2] = lo2f(v.y);
        sH[r][c4 + 3] = hi2f(v.y);
    }
    __syncthreads();
    int r = tid & 63;
    int c0 = (tid >> 6) * 10;
    float acc[10];
#pragma unroll
    for (int j = 0; j < 10; j++) acc[j] = 0.f;
    for (int k = 0; k < NHID; k++) {
        float a = sH[r][k];
#pragma unroll
        for (int j = 0; j < 10; j++) acc[j] += a * sW[k * NCLS + c0 + j];
    }
    int gr = row0 + r;
    if (gr < N) {
#pragma unroll
        for (int j = 0; j < 10; j++) out[(size_t)gr * NCLS + c0 + j] = acc[j];
    }
}

// ---------------- SpMM2: out = A_norm @ h2 + b2 ----------------
__global__ __launch_bounds__(256) void spmm2(const float* __restrict__ h2,
                                             const int* __restrict__ rowptr,
                                             const int2* __restrict__ csr,
                                             const float* __restrict__ dis,
                                             const float* __restrict__ b2,
                                             float* __restrict__ out, int N) {
    int tid = threadIdx.x;
    int node = blockIdx.x * 32 + (tid >> 3);
    int g = tid & 7;
    if (node >= N) return;
    int f0 = g * 5;
    float d = dis[node];
    float sc = d * d;
    float acc[5];
#pragma unroll
    for (int j = 0; j < 5; j++) acc[j] = sc * h2[(size_t)node * NCLS + f0 + j];
    int e0 = rowptr[node], e1 = rowptr[node + 1];
    int e = e0;
    for (; e + 1 < e1; e += 2) {
        int2 c0 = csr[e];
        int2 c1 = csr[e + 1];
        float n0 = __int_as_float(c0.y);
        float n1 = __int_as_float(c1.y);
#pragma unroll
        for (int j = 0; j < 5; j++) {
            acc[j] += n0 * h2[(size_t)c0.x * NCLS + f0 + j];
            acc[j] += n1 * h2[(size_t)c1.x * NCLS + f0 + j];
        }
    }
    if (e < e1) {
        int2 c0 = csr[e];
        float nm = __int_as_float(c0.y);
#pragma unroll
        for (int j = 0; j < 5; j++) acc[j] += nm * h2[(size_t)c0.x * NCLS + f0 + j];
    }
#pragma unroll
    for (int j = 0; j < 5; j++) out[(size_t)node * NCLS + f0 + j] = acc[j] + b2[f0 + j];
}

extern "C" void kernel_launch(void* const* d_in, const int* in_sizes, int n_in,
                              void* d_out, int out_size, void* d_ws, size_t ws_size,
                              hipStream_t stream) {
    const float* x   = (const float*)d_in[0];
    const int*  eidx = (const int*)d_in[1];
    const float* ew  = (const float*)d_in[2];
    const float* W1  = (const float*)d_in[3];
    const float* b1  = (const float*)d_in[4];
    const float* W2  = (const float*)d_in[5];
    const float* b2  = (const float*)d_in[6];
    float* out = (float*)d_out;

    int N = in_sizes[0] / NFEAT;     // 100000
    int E = in_sizes[2];             // 3200000
    const int* row = eidx;
    const int* col = eidx + E;

    char* p = (char*)d_ws;
    auto alloc = [&](size_t bytes) {
        char* q = p;
        p += (bytes + 255) & ~(size_t)255;
        return q;
    };
    ull_t*    degcnt   = (ull_t*)   alloc((size_t)N * DPAD * 8);   // 12.8 MB padded
    float*    dis      = (float*)   alloc((size_t)N * 4);
    int*      rank     = (int*)     alloc((size_t)E * 4);
    int*      rowptr   = (int*)     alloc((size_t)(N + 1) * 4);
    int*      bsums    = (int*)     alloc(512 * 4);
    int2*     csr      = (int2*)    alloc((size_t)E * 8);
    ushort_t* W1T      = (ushort_t*)alloc((size_t)NFEAT * NHID * 2);
    ushort_t* h1       = (ushort_t*)alloc((size_t)N * NHID * 2);
    ushort_t* hrelu    = (ushort_t*)alloc((size_t)N * NHID * 2);
    float*    h2       = (float*)   alloc((size_t)N * NCLS * 4);

    hipMemsetAsync(degcnt, 0, (size_t)N * DPAD * 8, stream);

    int eb = (E + 255) / 256;
    int nb = (N + 255) / 256;

    w1t_kernel<<<(NFEAT * NHID) / 256, 256, 0, stream>>>(W1, W1T);
    edge_rank_deg<<<eb, 256, 0, stream>>>(col, ew, degcnt, rank, E);
    dis_kernel<<<nb, 256, 0, stream>>>(degcnt, dis, N);
    scan_blocks<<<nb, 256, 0, stream>>>(degcnt, rowptr, bsums, N);
    scan_bsums<<<1, 512, 0, stream>>>(bsums, nb);
    add_offsets<<<nb, 256, 0, stream>>>(rowptr, bsums, N, E);
    scatter_edges<<<eb, 256, 0, stream>>>(row, col, ew, rank, rowptr, dis, csr, E);
    gemm1_mfma<<<(N + G_BM - 1) / G_BM, 256, 0, stream>>>(x, W1T, h1, N);
    spmm1<<<(N + 7) / 8, 256, 0, stream>>>(h1, rowptr, csr, dis, b1, hrelu, N);
    gemm2<<<(N + 63) / 64, 256, 0, stream>>>(hrelu, W2, h2, N);
    spmm2<<<(N + 31) / 32, 256, 0, stream>>>(h2, rowptr, csr, dis, b2, out, N);
}

// Round 5
// 796.069 us; speedup vs baseline: 1.8258x; 1.0850x over previous
//
#include <hip/hip_runtime.h>

// GCN: N=100000 nodes, E=3.2M edges, 512 -> 128 (relu) -> 40
// Pipeline: W1T(bf16) -> megaA{edge rank+deg atomics || GEMM1 MFMA, block-interleaved}
//           -> scan(+dis) -> scan_bsums -> add_offsets -> scatter
//           -> SpMM1+GEMM2 fused -> SpMM2(+b2)

#define NFEAT 512
#define NHID  128
#define NCLS  40
#define DPAD  16

typedef unsigned short ushort_t;
typedef unsigned int uint_t;
typedef unsigned long long ull_t;

#define WSCALE 2097152.0f
#define WINV   (1.0f / 2097152.0f)

__device__ inline ushort_t f2bf(float f) {
    uint_t u = __float_as_uint(f);
    u += 0x7fffu + ((u >> 16) & 1u);
    return (ushort_t)(u >> 16);
}
__device__ inline uint_t pk2(float a, float b) {
    return (uint_t)f2bf(a) | ((uint_t)f2bf(b) << 16);
}
__device__ inline float lo2f(uint_t u) { return __uint_as_float(u << 16); }
__device__ inline float hi2f(uint_t u) { return __uint_as_float(u & 0xffff0000u); }

__global__ void w1t_kernel(const float* __restrict__ W1, ushort_t* __restrict__ W1T) {
    int idx = blockIdx.x * 256 + threadIdx.x;
    int k = idx >> 7, n = idx & 127;
    W1T[n * NFEAT + k] = f2bf(W1[idx]);
}

#define G_BM 128
#define G_BK 64
#define LDA  72

using f32x4  = __attribute__((ext_vector_type(4))) float;
using s16x8  = __attribute__((ext_vector_type(8))) short;

__global__ __launch_bounds__(256) void mega_a(const float* __restrict__ x,
                                              const ushort_t* __restrict__ W1T,
                                              ushort_t* __restrict__ h1, int N, int GB,
                                              const int* __restrict__ col,
                                              const float* __restrict__ w,
                                              ull_t* __restrict__ degcnt,
                                              int* __restrict__ rank, int E, int EB) {
    int b = blockIdx.x;
    int tid = threadIdx.x;
    if (b % 17 == 16) {
        int g = b / 17;
        if (g >= GB) return;
        __shared__ ushort_t sA[G_BM * LDA];
        int row0 = g * G_BM;
        int wave = tid >> 6, lane = tid & 63;
        int wm = wave >> 1, wn = wave & 1;
        int lm = lane & 15, quad = lane >> 4;

        f32x4 acc[4][4] = {};

        int sr = tid >> 1;
        int sk = (tid & 1) * 32;
        int gr_st = row0 + sr;
        bool rvalid = gr_st < N;
        const float* xrow = x + (size_t)(rvalid ? gr_st : row0) * NFEAT;

        for (int k0 = 0; k0 < NFEAT; k0 += G_BK) {
            const float4* xv = (const float4*)(xrow + k0 + sk);
#pragma unroll
            for (int q = 0; q < 4; q++) {
                float4 a = xv[2 * q];
                float4 bb = xv[2 * q + 1];
                if (!rvalid) { a = make_float4(0,0,0,0); bb = make_float4(0,0,0,0); }
                uint4 pk;
                pk.x = pk2(a.x, a.y);
                pk.y = pk2(a.z, a.w);
                pk.z = pk2(bb.x, bb.y);
                pk.w = pk2(bb.z, bb.w);
                *(uint4*)&sA[sr * LDA + sk + q * 8] = pk;
            }
            __syncthreads();
#pragma unroll
            for (int kk = 0; kk < G_BK; kk += 32) {
                s16x8 af[4], bf[4];
#pragma unroll
                for (int i = 0; i < 4; i++) {
                    int m = wm * 64 + i * 16 + lm;
                    af[i] = *(const s16x8*)&sA[m * LDA + kk + quad * 8];
                }
#pragma unroll
                for (int j = 0; j < 4; j++) {
                    int n = wn * 64 + j * 16 + lm;
                    bf[j] = *(const s16x8*)&W1T[(size_t)n * NFEAT + k0 + kk + quad * 8];
                }
#pragma unroll
                for (int i = 0; i < 4; i++)
#pragma unroll
                    for (int j = 0; j < 4; j++)
                        acc[i][j] = __builtin_amdgcn_mfma_f32_16x16x32_bf16(af[i], bf[j], acc[i][j], 0, 0, 0);
            }
            __syncthreads();
        }

#pragma unroll
        for (int i = 0; i < 4; i++) {
            int rbase = row0 + wm * 64 + i * 16 + quad * 4;
#pragma unroll
            for (int r = 0; r < 4; r++) {
                int gr = rbase + r;
                if (gr < N) {
#pragma unroll
                    for (int j = 0; j < 4; j++) {
                        int colx = wn * 64 + j * 16 + lm;
                        h1[(size_t)gr * NHID + colx] = f2bf(acc[i][j][r]);
                    }
                }
            }
        }
    } else {
        int ebk = b - b / 17;
        if (ebk >= EB) return;
        int e = ebk * 256 + tid;
        if (e < E) {
            ull_t pk = (1ULL << 32) | (ull_t)__float2uint_rn(w[e] * WSCALE);
            ull_t old = atomicAdd(&degcnt[(size_t)col[e] * DPAD], pk);
            rank[e] = (int)(old >> 32);
        }
    }
}

__global__ void scan_blocks(const ull_t* __restrict__ degcnt, int* __restrict__ rowptr,
                            int* __restrict__ bsums, float* __restrict__ dis, int N) {
    __shared__ int s[256];
    int tid = threadIdx.x;
    int i = blockIdx.x * 256 + tid;
    ull_t dc = (i < N) ? degcnt[(size_t)i * DPAD] : 0ULL;
    int v = (int)(dc >> 32);
    if (i < N) {
        float deg = (float)(uint_t)dc * WINV;
        dis[i] = rsqrtf(deg + 1.0f);
    }
    s[tid] = v;
    __syncthreads();
    for (int off = 1; off < 256; off <<= 1) {
        int t = (tid >= off) ? s[tid - off] : 0;
        __syncthreads();
        s[tid] += t;
        __syncthreads();
    }
    if (i < N) rowptr[i] = s[tid] - v;
    if (tid == 255) bsums[blockIdx.x] = s[255];
}

__global__ void scan_bsums(int* __restrict__ bsums, int nb) {
    __shared__ int s[512];
    int t = threadIdx.x;
    int v = (t < nb) ? bsums[t] : 0;
    s[t] = v;
    __syncthreads();
    for (int off = 1; off < 512; off <<= 1) {
        int u = (t >= off) ? s[t - off] : 0;
        __syncthreads();
        s[t] += u;
        __syncthreads();
    }
    if (t < nb) bsums[t] = s[t] - v;
}

__global__ void add_offsets(int* __restrict__ rowptr, const int* __restrict__ bsums,
                            int N, int E) {
    int i = blockIdx.x * 256 + threadIdx.x;
    if (i < N) rowptr[i] += bsums[blockIdx.x];
    if (i == 0) rowptr[N] = E;
}

__global__ void scatter_edges(const int* __restrict__ row, const int* __restrict__ col,
                              const float* __restrict__ w, const int* __restrict__ rank,
                              const int* __restrict__ rowptr, const float* __restrict__ dis,
                              int2* __restrict__ csr, int E) {
    int e = blockIdx.x * 256 + threadIdx.x;
    if (e < E) {
        int r = row[e], c = col[e];
        int pos = rowptr[c] + rank[e];
        float nm = dis[r] * w[e] * dis[c];
        csr[pos] = make_int2(r, __float_as_int(nm));
    }
}

// SpMM1 + GEMM2 fused. Phase 1: aggregate -> relu -> LDS fp32. Phase 2: @W2 from LDS.
#define SPB 8
__global__ __launch_bounds__(256) void spmm1_fused(const ushort_t* __restrict__ h1,
                                                   const int* __restrict__ rowptr,
                                                   const int2* __restrict__ csr,
                                                   const float* __restrict__ dis,
                                                   const float* __restrict__ b1,
                                                   const float* __restrict__ W2,
                                                   float* __restrict__ h2, int N) {
    __shared__ float sH[SPB][132];
    __shared__ float sW[NHID * NCLS];
    int tid = threadIdx.x;
    for (int i = tid; i < NHID * NCLS; i += 256) sW[i] = W2[i];

    int node = blockIdx.x * SPB + (tid >> 5);
    int lane = tid & 31;
    bool valid = node < N;

    float a0 = 0.f, a1 = 0.f, a2 = 0.f, a3 = 0.f;
    if (valid) {
        const uint2* hv = (const uint2*)h1;
        float d = dis[node];
        float sc = d * d;
        uint2 sv = hv[(size_t)node * 32 + lane];
        a0 = sc * lo2f(sv.x); a1 = sc * hi2f(sv.x);
        a2 = sc * lo2f(sv.y); a3 = sc * hi2f(sv.y);
        int e0 = rowptr[node], e1 = rowptr[node + 1];
        int e = e0;
        for (; e + 3 < e1; e += 4) {
            int2 c0 = csr[e],     c1 = csr[e + 1];
            int2 c2 = csr[e + 2], c3 = csr[e + 3];
            uint2 v0 = hv[(size_t)c0.x * 32 + lane];
            uint2 v1 = hv[(size_t)c1.x * 32 + lane];
            uint2 v2 = hv[(size_t)c2.x * 32 + lane];
            uint2 v3 = hv[(size_t)c3.x * 32 + lane];
            float n0 = __int_as_float(c0.y), n1 = __int_as_float(c1.y);
            float n2 = __int_as_float(c2.y), n3 = __int_as_float(c3.y);
            a0 += n0 * lo2f(v0.x); a1 += n0 * hi2f(v0.x);
            a2 += n0 * lo2f(v0.y); a3 += n0 * hi2f(v0.y);
            a0 += n1 * lo2f(v1.x); a1 += n1 * hi2f(v1.x);
            a2 += n1 * lo2f(v1.y); a3 += n1 * hi2f(v1.y);
            a0 += n2 * lo2f(v2.x); a1 += n2 * hi2f(v2.x);
            a2 += n2 * lo2f(v2.y); a3 += n2 * hi2f(v2.y);
            a0 += n3 * lo2f(v3.x); a1 += n3 * hi2f(v3.x);
            a2 += n3 * lo2f(v3.y); a3 += n3 * hi2f(v3.y);
        }
        for (; e < e1; e++) {
            int2 c0 = csr[e];
            uint2 v0 = hv[(size_t)c0.x * 32 + lane];
            float n0 = __int_as_float(c0.y);
            a0 += n0 * lo2f(v0.x); a1 += n0 * hi2f(v0.x);
            a2 += n0 * lo2f(v0.y); a3 += n0 * hi2f(v0.y);
        }
        const float4 bb = ((const float4*)b1)[lane];
        a0 = fmaxf(a0 + bb.x, 0.f);
        a1 = fmaxf(a1 + bb.y, 0.f);
        a2 = fmaxf(a2 + bb.z, 0.f);
        a3 = fmaxf(a3 + bb.w, 0.f);
    }
    *(float4*)&sH[tid >> 5][4 * lane] = make_float4(a0, a1, a2, a3);
    __syncthreads();

    int node0 = blockIdx.x * SPB;
    for (int o = tid; o < SPB * NCLS; o += 256) {
        int n = o / NCLS, c = o - n * NCLS;
        int gn = node0 + n;
        if (gn < N) {
            float acc = 0.f;                       // b2 added after aggregation (spmm2)
#pragma unroll 4
            for (int k = 0; k < NHID; k++) acc += sH[n][k] * sW[k * NCLS + c];
            h2[(size_t)gn * NCLS + c] = acc;
        }
    }
}

__global__ __launch_bounds__(256) void spmm2(const float* __restrict__ h2,
                                             const int* __restrict__ rowptr,
                                             const int2* __restrict__ csr,
                                             const float* __restrict__ dis,
                                             const float* __restrict__ b2,
                                             float* __restrict__ out, int N) {
    int tid = threadIdx.x;
    int node = blockIdx.x * 32 + (tid >> 3);
    int g = tid & 7;
    if (node >= N) return;
    int f0 = g * 5;
    float d = dis[node];
    float sc = d * d;
    float acc[5];
#pragma unroll
    for (int j = 0; j < 5; j++) acc[j] = sc * h2[(size_t)node * NCLS + f0 + j];
    int e0 = rowptr[node], e1 = rowptr[node + 1];
    int e = e0;
    for (; e + 1 < e1; e += 2) {
        int2 c0 = csr[e];
        int2 c1 = csr[e + 1];
        float n0 = __int_as_float(c0.y);
        float n1 = __int_as_float(c1.y);
#pragma unroll
        for (int j = 0; j < 5; j++) {
            acc[j] += n0 * h2[(size_t)c0.x * NCLS + f0 + j];
            acc[j] += n1 * h2[(size_t)c1.x * NCLS + f0 + j];
        }
    }
    if (e < e1) {
        int2 c0 = csr[e];
        float nm = __int_as_float(c0.y);
#pragma unroll
        for (int j = 0; j < 5; j++) acc[j] += nm * h2[(size_t)c0.x * NCLS + f0 + j];
    }
#pragma unroll
    for (int j = 0; j < 5; j++) out[(size_t)node * NCLS + f0 + j] = acc[j] + b2[f0 + j];
}

extern "C" void kernel_launch(void* const* d_in, const int* in_sizes, int n_in,
                              void* d_out, int out_size, void* d_ws, size_t ws_size,
                              hipStream_t stream) {
    const float* x   = (const float*)d_in[0];
    const int*  eidx = (const int*)d_in[1];
    const float* ew  = (const float*)d_in[2];
    const float* W1  = (const float*)d_in[3];
    const float* b1  = (const float*)d_in[4];
    const float* W2  = (const float*)d_in[5];
    const float* b2  = (const float*)d_in[6];
    float* out = (float*)d_out;

    int N = in_sizes[0] / NFEAT;
    int E = in_sizes[2];
    const int* row = eidx;
    const int* col = eidx + E;

    char* p = (char*)d_ws;
    auto alloc = [&](size_t bytes) {
        char* q = p;
        p += (bytes + 255) & ~(size_t)255;
        return q;
    };
    ull_t*    degcnt   = (ull_t*)   alloc((size_t)N * DPAD * 8);
    float*    dis      = (float*)   alloc((size_t)N * 4);
    int*      rank     = (int*)     alloc((size_t)E * 4);
    int*      rowptr   = (int*)     alloc((size_t)(N + 1) * 4);
    int*      bsums    = (int*)     alloc(512 * 4);
    int2*     csr      = (int2*)    alloc((size_t)E * 8);
    ushort_t* W1T      = (ushort_t*)alloc((size_t)NFEAT * NHID * 2);
    ushort_t* h1       = (ushort_t*)alloc((size_t)N * NHID * 2);
    float*    h2       = (float*)   alloc((size_t)N * NCLS * 4);

    hipMemsetAsync(degcnt, 0, (size_t)N * DPAD * 8, stream);

    int eb = (E + 255) / 256;
    int nb = (N + 255) / 256;
    int gb = (N + G_BM - 1) / G_BM;

    int T = 17 * gb;
    if (T - T / 17 < eb) T = (eb * 17 + 15) / 16 + 17;

    w1t_kernel<<<(NFEAT * NHID) / 256, 256, 0, stream>>>(W1, W1T);
    mega_a<<<T, 256, 0, stream>>>(x, W1T, h1, N, gb, col, ew, degcnt, rank, E, eb);
    scan_blocks<<<nb, 256, 0, stream>>>(degcnt, rowptr, bsums, dis, N);
    scan_bsums<<<1, 512, 0, stream>>>(bsums, nb);
    add_offsets<<<nb, 256, 0, stream>>>(rowptr, bsums, N, E);
    scatter_edges<<<eb, 256, 0, stream>>>(row, col, ew, rank, rowptr, dis, csr, E);
    spmm1_fused<<<(N + SPB - 1) / SPB, 256, 0, stream>>>(h1, rowptr, csr, dis, b1, W2, h2, N);
    spmm2<<<(N + 31) / 32, 256, 0, stream>>>(h2, rowptr, csr, dis, b2, out, N);
}